// Round 1
// baseline (1480.846 us; speedup 1.0000x reference)
//
#include <hip/hip_runtime.h>
#include <stdint.h>

// Problem constants (from reference): TOKENS x IN_F @ (OUT_F x IN_F)^T
#define M_TOK 8192
#define K_IN  4096
#define N_OUT 11008
// group size = 128 -> K_IN/128 = 32 groups

typedef float f32x4 __attribute__((ext_vector_type(4)));
typedef __bf16 bf16x8 __attribute__((ext_vector_type(8)));

typedef const uint32_t __attribute__((address_space(1)))* gas_ptr;
typedef uint32_t __attribute__((address_space(3)))* las_ptr;

__device__ __forceinline__ uint16_t f2bf(float f) {
  // round-to-nearest-even fp32 -> bf16 (inputs are finite normals)
  uint32_t u = __float_as_uint(f);
  return (uint16_t)((u + 0x7fffu + ((u >> 16) & 1u)) >> 16);
}

// ---- pass 1a: x_bf16[t,k] = bf16(qx[t,k] * sx[t]) ----
__global__ __launch_bounds__(256) void dequant_x_kernel(
    const float* __restrict__ qx, const float* __restrict__ sx,
    uint16_t* __restrict__ out) {
  int idx = blockIdx.x * 256 + threadIdx.x;   // float4 index; K=4096 -> 1024 f4/row
  int row = idx >> 10;
  float s = sx[row];
  float4 v = reinterpret_cast<const float4*>(qx)[idx];
  ushort4 o;
  o.x = f2bf(v.x * s);
  o.y = f2bf(v.y * s);
  o.z = f2bf(v.z * s);
  o.w = f2bf(v.w * s);
  reinterpret_cast<ushort4*>(out)[idx] = o;
}

// ---- pass 1b: w_bf16[o,k] = bf16((w[o,k] - off[o,k/128]) * scl[o,k/128]) ----
__global__ __launch_bounds__(256) void dequant_w_kernel(
    const float* __restrict__ w, const float* __restrict__ scl,
    const float* __restrict__ off, uint16_t* __restrict__ out) {
  int idx = blockIdx.x * 256 + threadIdx.x;   // float4 index
  int rg = idx >> 5;                          // (idx*4)/128 = row*32 + group
  float s = scl[rg];
  float o = off[rg];
  float4 v = reinterpret_cast<const float4*>(w)[idx];
  ushort4 u;
  u.x = f2bf((v.x - o) * s);
  u.y = f2bf((v.y - o) * s);
  u.z = f2bf((v.z - o) * s);
  u.w = f2bf((v.w - o) * s);
  reinterpret_cast<ushort4*>(out)[idx] = u;
}

// ---- pass 2: C[M,N] = A[M,K] * B[N,K]^T, bf16 in / fp32 out ----
// m97 structure: 128x128 tile, BK=64, 256 thr = 4 waves, each wave 64x64 via
// 4x4 grid of 16x16x32 MFMAs. global_load_lds width=16 staging; XOR-swizzled
// 16B chunks in LDS (chunk c of row r lives at slot c^(r&7)) to kill the
// 16-way ds_read_b128 bank conflict of a plain 128B-row layout.
__global__ __launch_bounds__(256) void gemm_bt_kernel(
    const uint16_t* __restrict__ A,   // [M,K] bf16 bits
    const uint16_t* __restrict__ B,   // [N,K] bf16 bits
    float* __restrict__ C) {          // [M,N] fp32
  constexpr int K = K_IN;
  constexpr int N = N_OUT;

  __shared__ uint16_t sA[128 * 64];   // 16 KiB
  __shared__ uint16_t sB[128 * 64];   // 16 KiB

  const int tid  = threadIdx.x;
  const int lane = tid & 63;
  const int wave = tid >> 6;
  const int wm = wave >> 1;           // wave quadrant: rows
  const int wn = wave & 1;            // wave quadrant: cols

  const int blockN = blockIdx.x * 128;
  const int blockM = blockIdx.y * 128;

  f32x4 acc[4][4];
#pragma unroll
  for (int i = 0; i < 4; ++i)
#pragma unroll
    for (int j = 0; j < 4; ++j) acc[i][j] = {0.f, 0.f, 0.f, 0.f};

  // Staging source pointers. LDS slot p = i*256 + tid (16B chunks, 8/row).
  // Slot (r, c_lds) holds global chunk c_g = c_lds ^ (r&7).
  const uint16_t* aSrc[4];
  const uint16_t* bSrc[4];
#pragma unroll
  for (int i = 0; i < 4; ++i) {
    int p = i * 256 + tid;
    int r = p >> 3;
    int cg = (p & 7) ^ (r & 7);
    aSrc[i] = A + (size_t)(blockM + r) * K + cg * 8;
    bSrc[i] = B + (size_t)(blockN + r) * K + cg * 8;
  }

  for (int k0 = 0; k0 < K; k0 += 64) {
    __syncthreads();                       // LDS free to overwrite
#pragma unroll
    for (int i = 0; i < 4; ++i) {
      // wave-uniform LDS base; HW places lane l at base + l*16
      __builtin_amdgcn_global_load_lds((gas_ptr)(const void*)(aSrc[i] + k0),
                                       (las_ptr)(void*)(sA + (i * 256 + wave * 64) * 8),
                                       16, 0, 0);
      __builtin_amdgcn_global_load_lds((gas_ptr)(const void*)(bSrc[i] + k0),
                                       (las_ptr)(void*)(sB + (i * 256 + wave * 64) * 8),
                                       16, 0, 0);
    }
    __syncthreads();                       // drains vmcnt -> tiles visible

#pragma unroll
    for (int ks = 0; ks < 2; ++ks) {
      const int kc = ks * 4 + (lane >> 4);   // 16B chunk index 0..7 within row
      bf16x8 af[4], bfv[4];
#pragma unroll
      for (int mi = 0; mi < 4; ++mi) {
        int r = wm * 64 + mi * 16 + (lane & 15);
        af[mi] = *reinterpret_cast<const bf16x8*>(sA + r * 64 + ((kc ^ (r & 7)) << 3));
      }
#pragma unroll
      for (int ni = 0; ni < 4; ++ni) {
        int r = wn * 64 + ni * 16 + (lane & 15);
        bfv[ni] = *reinterpret_cast<const bf16x8*>(sB + r * 64 + ((kc ^ (r & 7)) << 3));
      }
#pragma unroll
      for (int mi = 0; mi < 4; ++mi)
#pragma unroll
        for (int ni = 0; ni < 4; ++ni)
          acc[mi][ni] = __builtin_amdgcn_mfma_f32_16x16x32_bf16(
              af[mi], bfv[ni], acc[mi][ni], 0, 0, 0);
    }
  }

  // Epilogue: C/D layout (16x16x32): col = lane&15, row = (lane>>4)*4 + reg
  const int crow0 = blockM + wm * 64 + (lane >> 4) * 4;
  const int ccol0 = blockN + wn * 64 + (lane & 15);
#pragma unroll
  for (int mi = 0; mi < 4; ++mi)
#pragma unroll
    for (int ni = 0; ni < 4; ++ni) {
#pragma unroll
      for (int v = 0; v < 4; ++v) {
        C[(size_t)(crow0 + mi * 16 + v) * N + (ccol0 + ni * 16)] = acc[mi][ni][v];
      }
    }
}

extern "C" void kernel_launch(void* const* d_in, const int* in_sizes, int n_in,
                              void* d_out, int out_size, void* d_ws, size_t ws_size,
                              hipStream_t stream) {
  const float* qx   = (const float*)d_in[0];  // [8192, 4096]
  const float* sx   = (const float*)d_in[1];  // [8192, 1]
  const float* w    = (const float*)d_in[2];  // [11008, 4096]
  const float* wscl = (const float*)d_in[3];  // [11008, 32]
  const float* woff = (const float*)d_in[4];  // [11008, 32]
  float* out = (float*)d_out;                 // [8192, 11008]

  // workspace: A_bf16 (64 MiB) then B_bf16 (86 MiB); needs ~150.6 MiB
  uint16_t* Abf = (uint16_t*)d_ws;
  uint16_t* Bbf = Abf + (size_t)M_TOK * K_IN;

  {
    int n4 = M_TOK * K_IN / 4;                 // 8,388,608
    dequant_x_kernel<<<n4 / 256, 256, 0, stream>>>(qx, sx, Abf);
  }
  {
    int n4 = (int)((size_t)N_OUT * K_IN / 4);  // 11,272,192
    dequant_w_kernel<<<n4 / 256, 256, 0, stream>>>(w, wscl, woff, Bbf);
  }
  {
    dim3 grid(N_OUT / 128, M_TOK / 128);       // 86 x 64
    gemm_bt_kernel<<<grid, 256, 0, stream>>>(Abf, Bbf, out);
  }
}